// Round 6
// baseline (72.331 us; speedup 1.0000x reference)
//
#include <hip/hip_runtime.h>

// ---------------- workspace layout ----------------
// float ws[0..144)        : per-block partial L1 sums
// uint  ws[256..400)      : completion flags (MAGIC when partial published)
#define FLAG_OFF 256
#define MAGICF   0x5EEDF00Du

__device__ __forceinline__ int clip71(int v) { return v < 0 ? 0 : (v > 71 ? 71 : v); }

#define W0 (-0.09375f)
#define W1 (0.59375f)
#define W2 (0.59375f)
#define W3 (-0.09375f)

// ---------------- single fused kernel ---------------------------------------
// 144 blocks x 1024 threads (16 waves). Block bi: b = bi/36, n in
// [ (bi%36)*16, +16 ), one n per wave.
// P0: per-PIXEL bicubic downsample of batch b into LDS (gt2: 3x36x36,
//     gt4: 3x18x18), spread across all 16 waves. fp order identical to
//     reference: H-pass (sequential k) then W-pass (sequential k).
// P1: g<576: p2 gram from gt; g in [576,756): gram of LDS downsampled patch;
//     g in [960,976): the block's 16 p1 grams from x (wave 15, concurrent ->
//     critical path is ONE global-gram, not two as in round 5).
//     Gram: sequential e, /27.0f true division, symmetric halves bitwise-eq.
// P2: one wave per n sweeps 756 candidates from LDS (stride-9 = 2-way bank
//     aliasing, free), argmin w/ first-index tie-break, L1 partial.
// Completion: each block publishes partial + MAGIC flag (agent scope);
// block 0 wave 0 polls all 144 flags, reduces, writes out. One dispatch total.
__global__ void __launch_bounds__(1024)
fused_kernel(const float* __restrict__ x, const float* __restrict__ gt,
             float* __restrict__ ws, float* __restrict__ out) {
    __shared__ float gt2s[3 * 36 * 36];   // 15552 B
    __shared__ float gt4s[3 * 18 * 18];   //  3888 B
    __shared__ float qsm[756 * 9];        // 27216 B
    __shared__ float p1sm[16 * 9];        //   576 B
    __shared__ float wpart[16];

    const int bi = blockIdx.x;
    const int b  = bi / 36;
    const int group = bi - b * 36;        // n = group*16 + waveid

    // ---------------- P0: downsampled pixels into LDS -----------------------
    for (int p = threadIdx.x; p < 3888 + 972; p += 1024) {
        if (p < 3888) {
            int c = p / 1296; int r = p - c * 1296; int oh = r / 36; int ow = r - oh * 36;
            const float* src = gt + (b * 3 + c) * 5184;
            int r0 = clip71(2*oh - 1) * 72, r1 = (2*oh) * 72, r2 = (2*oh + 1) * 72, r3 = clip71(2*oh + 2) * 72;
            int c0 = clip71(2*ow - 1),      c1 = 2*ow,        c2 = 2*ow + 1,        c3 = clip71(2*ow + 2);
            float t0, t1, t2, t3, o;
            t0  = W0 * src[r0 + c0]; t0 += W1 * src[r1 + c0]; t0 += W2 * src[r2 + c0]; t0 += W3 * src[r3 + c0];
            t1  = W0 * src[r0 + c1]; t1 += W1 * src[r1 + c1]; t1 += W2 * src[r2 + c1]; t1 += W3 * src[r3 + c1];
            t2  = W0 * src[r0 + c2]; t2 += W1 * src[r1 + c2]; t2 += W2 * src[r2 + c2]; t2 += W3 * src[r3 + c2];
            t3  = W0 * src[r0 + c3]; t3 += W1 * src[r1 + c3]; t3 += W2 * src[r2 + c3]; t3 += W3 * src[r3 + c3];
            o  = W0 * t0; o += W1 * t1; o += W2 * t2; o += W3 * t3;
            gt2s[p] = o;
        } else {
            int u = p - 3888;
            int c = u / 324; int r = u - c * 324; int oh = r / 18; int ow = r - oh * 18;
            const float* src = gt + (b * 3 + c) * 5184;
            const float* q = src + (4 * oh) * 72 + 4 * ow;
            float t0, t1, t2, t3, o;
            t0  = W0 * q[0]; t0 += W1 * q[72]; t0 += W2 * q[144]; t0 += W3 * q[216];
            t1  = W0 * q[1]; t1 += W1 * q[73]; t1 += W2 * q[145]; t1 += W3 * q[217];
            t2  = W0 * q[2]; t2 += W1 * q[74]; t2 += W2 * q[146]; t2 += W3 * q[218];
            t3  = W0 * q[3]; t3 += W1 * q[75]; t3 += W2 * q[147]; t3 += W3 * q[219];
            o  = W0 * t0; o += W1 * t1; o += W2 * t2; o += W3 * t3;
            gt4s[u] = o;
        }
    }
    __syncthreads();

    // ---------------- P1: grams into LDS ------------------------------------
    {
        const int g = threadIdx.x;
        if (g < 576) {
            // p2 gram from gt
            int ph = g / 24, pw = g - ph * 24;
            const float* base = gt + b * 15552 + (3 * ph) * 72 + 3 * pw;
            float pix[3][9];
            #pragma unroll
            for (int c = 0; c < 3; ++c)
                #pragma unroll
                for (int i = 0; i < 3; ++i)
                    #pragma unroll
                    for (int j = 0; j < 3; ++j)
                        pix[c][i * 3 + j] = base[c * 5184 + i * 72 + j];
            #pragma unroll
            for (int c = 0; c < 3; ++c)
                #pragma unroll
                for (int d = c; d < 3; ++d) {
                    float s = 0.0f;
                    #pragma unroll
                    for (int e = 0; e < 9; ++e) s += pix[c][e] * pix[d][e];
                    s = s / 27.0f;
                    qsm[g * 9 + c * 3 + d] = s;
                    qsm[g * 9 + d * 3 + c] = s;
                }
        } else if (g < 756) {
            // gram of 3x3 patch of LDS-resident downsampled image
            float pix[3][9];
            if (g < 720) {
                int n2 = g - 576;
                int ph = n2 / 12, pw = n2 - ph * 12;
                #pragma unroll
                for (int c = 0; c < 3; ++c)
                    #pragma unroll
                    for (int i = 0; i < 3; ++i)
                        #pragma unroll
                        for (int j = 0; j < 3; ++j)
                            pix[c][i * 3 + j] = gt2s[c * 1296 + (3 * ph + i) * 36 + (3 * pw + j)];
            } else {
                int n2 = g - 720;
                int ph = n2 / 6, pw = n2 - ph * 6;
                #pragma unroll
                for (int c = 0; c < 3; ++c)
                    #pragma unroll
                    for (int i = 0; i < 3; ++i)
                        #pragma unroll
                        for (int j = 0; j < 3; ++j)
                            pix[c][i * 3 + j] = gt4s[c * 324 + (3 * ph + i) * 18 + (3 * pw + j)];
            }
            #pragma unroll
            for (int c = 0; c < 3; ++c)
                #pragma unroll
                for (int d = c; d < 3; ++d) {
                    float s = 0.0f;
                    #pragma unroll
                    for (int e = 0; e < 9; ++e) s += pix[c][e] * pix[d][e];
                    s = s / 27.0f;
                    qsm[g * 9 + c * 3 + d] = s;
                    qsm[g * 9 + d * 3 + c] = s;
                }
        } else if (g >= 960 && g < 976) {
            // the block's 16 p1 grams from x (wave 15, otherwise idle in P1)
            int i = g - 960;
            int n = group * 16 + i;
            int ph = n / 24, pw = n - ph * 24;
            const float* base = x + b * 15552 + (3 * ph) * 72 + 3 * pw;
            float pix[3][9];
            #pragma unroll
            for (int c = 0; c < 3; ++c)
                #pragma unroll
                for (int ii = 0; ii < 3; ++ii)
                    #pragma unroll
                    for (int j = 0; j < 3; ++j)
                        pix[c][ii * 3 + j] = base[c * 5184 + ii * 72 + j];
            #pragma unroll
            for (int c = 0; c < 3; ++c)
                #pragma unroll
                for (int d = c; d < 3; ++d) {
                    float s = 0.0f;
                    #pragma unroll
                    for (int e = 0; e < 9; ++e) s += pix[c][e] * pix[d][e];
                    s = s / 27.0f;
                    p1sm[i * 9 + c * 3 + d] = s;
                    p1sm[i * 9 + d * 3 + c] = s;
                }
        }
    }
    __syncthreads();

    // ---------------- P2: score sweep, one wave per n ------------------------
    const int waveid = threadIdx.x >> 6;
    const int lane   = threadIdx.x & 63;
    const int n = group * 16 + waveid;

    float v1[9], v2[9];
    #pragma unroll
    for (int d = 0; d < 9; ++d) { v1[d] = p1sm[waveid * 9 + d]; v2[d] = qsm[n * 9 + d]; }
    float n1 = 0.0f, n2 = 0.0f;
    #pragma unroll
    for (int d = 0; d < 9; ++d) { n1 += v1[d] * v1[d]; n2 += v2[d] * v2[d]; }

    float best = 3.402823466e+38f;
    int bidx = 0x7fffffff;
    for (int m = lane; m < 756; m += 64) {
        const float* q = qsm + m * 9;
        float nq = 0.0f, d1 = 0.0f, d2 = 0.0f;
        #pragma unroll
        for (int d = 0; d < 9; ++d) {
            float qv = q[d];
            nq += qv * qv; d1 += v1[d] * qv; d2 += v2[d] * qv;
        }
        float s = fmaxf((n1 + nq) - 2.0f * d1, 0.0f) + fmaxf((n2 + nq) - 2.0f * d2, 0.0f);
        if (s < best) { best = s; bidx = m; }       // strict <: first-min within lane
    }
    #pragma unroll
    for (int off = 32; off > 0; off >>= 1) {
        float ob = __shfl_down(best, off);
        int   oi = __shfl_down(bidx, off);
        if (ob < best || (ob == best && oi < bidx)) { best = ob; bidx = oi; }
    }
    if (lane == 0) {
        const float* q = qsm + bidx * 9;
        float s = 0.0f;
        #pragma unroll
        for (int d = 0; d < 9; ++d) s += fabsf(v1[d] - q[d]);
        wpart[waveid] = s;
    }
    __syncthreads();

    // ---------------- publish partial + flag (agent scope) -------------------
    if (threadIdx.x == 0) {
        float s = 0.0f;
        #pragma unroll
        for (int w = 0; w < 16; ++w) s += wpart[w];
        __hip_atomic_store(&ws[bi], s, __ATOMIC_RELAXED, __HIP_MEMORY_SCOPE_AGENT);
        __hip_atomic_store((unsigned*)ws + FLAG_OFF + bi, MAGICF,
                           __ATOMIC_RELEASE, __HIP_MEMORY_SCOPE_AGENT);
    }

    // ---------------- block 0, wave 0: wait for all partials, finalize -------
    if (bi == 0 && threadIdx.x < 64) {
        unsigned* flags = (unsigned*)ws + FLAG_OFF;
        bool mine;
        do {
            mine = true;
            for (int k = lane; k < 144; k += 64)
                mine = mine && (__hip_atomic_load(&flags[k], __ATOMIC_ACQUIRE,
                                                  __HIP_MEMORY_SCOPE_AGENT) == MAGICF);
        } while (!__all(mine ? 1 : 0));
        float s = 0.0f;
        for (int k = lane; k < 144; k += 64)
            s += __hip_atomic_load(&ws[k], __ATOMIC_RELAXED, __HIP_MEMORY_SCOPE_AGENT);
        #pragma unroll
        for (int off = 32; off > 0; off >>= 1) s += __shfl_down(s, off);
        if (lane == 0) out[0] = s / 20736.0f;
    }
}

extern "C" void kernel_launch(void* const* d_in, const int* in_sizes, int n_in,
                              void* d_out, int out_size, void* d_ws, size_t ws_size,
                              hipStream_t stream) {
    const float* x  = (const float*)d_in[0];
    const float* gt = (const float*)d_in[1];
    float* ws  = (float*)d_ws;
    float* out = (float*)d_out;

    fused_kernel<<<144, 1024, 0, stream>>>(x, gt, ws, out);
}

// Round 7
// 71.193 us; speedup vs baseline: 1.0160x; 1.0160x over previous
//
#include <hip/hip_runtime.h>

// ---------------- workspace layout (floats) ----------------
#define PART_OFF  0                     // 144 per-block partial L1 sums

__device__ __forceinline__ int clip71(int v) { return v < 0 ? 0 : (v > 71 ? 71 : v); }

#define W0 (-0.09375f)
#define W1 (0.59375f)
#define W2 (0.59375f)
#define W3 (-0.09375f)

// ---------------- fused kernel --------------------------------------------
// 144 blocks x 1024 threads (16 waves). Block bi: b = bi/36, handles n in
// [ (bi%36)*16, +16 ), one n per wave. (Round-5 structure = measured best;
// round-6's single-dispatch spin-wait variant regressed.)
// P0: per-PIXEL bicubic downsample of batch b into LDS (gt2 3x36x36,
//     gt4 3x18x18) across all 16 waves. fp order identical to reference:
//     H-pass (sequential k) then W-pass (sequential k).
// P1: g<576: p2 gram from gt; g in [576,756): gram of LDS downsampled patch;
//     g in [960,976): the block's 16 p1 grams from x (wave 15, concurrent,
//     so the critical path is ONE global-gram).
//     Gram: sequential e, /27.0f true division, symmetric halves bitwise-eq.
// P2: one wave per n sweeps 756 candidates from LDS (stride-9 = 2-way bank
//     aliasing, free), argmin w/ first-index tie-break, L1 partial -> one
//     plain store per block. No global atomics.
__global__ void __launch_bounds__(1024)
fused_kernel(const float* __restrict__ x, const float* __restrict__ gt,
             float* __restrict__ ws) {
    __shared__ float gt2s[3 * 36 * 36];   // 15552 B
    __shared__ float gt4s[3 * 18 * 18];   //  3888 B
    __shared__ float qsm[756 * 9];        // 27216 B
    __shared__ float p1sm[16 * 9];        //   576 B
    __shared__ float wpart[16];

    const int bi = blockIdx.x;
    const int b  = bi / 36;
    const int group = bi - b * 36;        // n = group*16 + waveid

    // ---------------- P0: downsampled pixels into LDS -----------------------
    for (int p = threadIdx.x; p < 3888 + 972; p += 1024) {
        if (p < 3888) {
            int c = p / 1296; int r = p - c * 1296; int oh = r / 36; int ow = r - oh * 36;
            const float* src = gt + (b * 3 + c) * 5184;
            int r0 = clip71(2*oh - 1) * 72, r1 = (2*oh) * 72, r2 = (2*oh + 1) * 72, r3 = clip71(2*oh + 2) * 72;
            int c0 = clip71(2*ow - 1),      c1 = 2*ow,        c2 = 2*ow + 1,        c3 = clip71(2*ow + 2);
            float t0, t1, t2, t3, o;
            t0  = W0 * src[r0 + c0]; t0 += W1 * src[r1 + c0]; t0 += W2 * src[r2 + c0]; t0 += W3 * src[r3 + c0];
            t1  = W0 * src[r0 + c1]; t1 += W1 * src[r1 + c1]; t1 += W2 * src[r2 + c1]; t1 += W3 * src[r3 + c1];
            t2  = W0 * src[r0 + c2]; t2 += W1 * src[r1 + c2]; t2 += W2 * src[r2 + c2]; t2 += W3 * src[r3 + c2];
            t3  = W0 * src[r0 + c3]; t3 += W1 * src[r1 + c3]; t3 += W2 * src[r2 + c3]; t3 += W3 * src[r3 + c3];
            o  = W0 * t0; o += W1 * t1; o += W2 * t2; o += W3 * t3;
            gt2s[p] = o;
        } else {
            int u = p - 3888;
            int c = u / 324; int r = u - c * 324; int oh = r / 18; int ow = r - oh * 18;
            const float* src = gt + (b * 3 + c) * 5184;
            const float* q = src + (4 * oh) * 72 + 4 * ow;
            float t0, t1, t2, t3, o;
            t0  = W0 * q[0]; t0 += W1 * q[72]; t0 += W2 * q[144]; t0 += W3 * q[216];
            t1  = W0 * q[1]; t1 += W1 * q[73]; t1 += W2 * q[145]; t1 += W3 * q[217];
            t2  = W0 * q[2]; t2 += W1 * q[74]; t2 += W2 * q[146]; t2 += W3 * q[218];
            t3  = W0 * q[3]; t3 += W1 * q[75]; t3 += W2 * q[147]; t3 += W3 * q[219];
            o  = W0 * t0; o += W1 * t1; o += W2 * t2; o += W3 * t3;
            gt4s[u] = o;
        }
    }
    __syncthreads();

    // ---------------- P1: grams into LDS ------------------------------------
    {
        const int g = threadIdx.x;
        if (g < 576) {
            // p2 gram from gt
            int ph = g / 24, pw = g - ph * 24;
            const float* base = gt + b * 15552 + (3 * ph) * 72 + 3 * pw;
            float pix[3][9];
            #pragma unroll
            for (int c = 0; c < 3; ++c)
                #pragma unroll
                for (int i = 0; i < 3; ++i)
                    #pragma unroll
                    for (int j = 0; j < 3; ++j)
                        pix[c][i * 3 + j] = base[c * 5184 + i * 72 + j];
            #pragma unroll
            for (int c = 0; c < 3; ++c)
                #pragma unroll
                for (int d = c; d < 3; ++d) {
                    float s = 0.0f;
                    #pragma unroll
                    for (int e = 0; e < 9; ++e) s += pix[c][e] * pix[d][e];
                    s = s / 27.0f;
                    qsm[g * 9 + c * 3 + d] = s;
                    qsm[g * 9 + d * 3 + c] = s;
                }
        } else if (g < 756) {
            // gram of 3x3 patch of LDS-resident downsampled image
            float pix[3][9];
            if (g < 720) {
                int n2 = g - 576;
                int ph = n2 / 12, pw = n2 - ph * 12;
                #pragma unroll
                for (int c = 0; c < 3; ++c)
                    #pragma unroll
                    for (int i = 0; i < 3; ++i)
                        #pragma unroll
                        for (int j = 0; j < 3; ++j)
                            pix[c][i * 3 + j] = gt2s[c * 1296 + (3 * ph + i) * 36 + (3 * pw + j)];
            } else {
                int n2 = g - 720;
                int ph = n2 / 6, pw = n2 - ph * 6;
                #pragma unroll
                for (int c = 0; c < 3; ++c)
                    #pragma unroll
                    for (int i = 0; i < 3; ++i)
                        #pragma unroll
                        for (int j = 0; j < 3; ++j)
                            pix[c][i * 3 + j] = gt4s[c * 324 + (3 * ph + i) * 18 + (3 * pw + j)];
            }
            #pragma unroll
            for (int c = 0; c < 3; ++c)
                #pragma unroll
                for (int d = c; d < 3; ++d) {
                    float s = 0.0f;
                    #pragma unroll
                    for (int e = 0; e < 9; ++e) s += pix[c][e] * pix[d][e];
                    s = s / 27.0f;
                    qsm[g * 9 + c * 3 + d] = s;
                    qsm[g * 9 + d * 3 + c] = s;
                }
        } else if (g >= 960 && g < 976) {
            // the block's 16 p1 grams from x (wave 15, otherwise idle in P1)
            int i = g - 960;
            int n = group * 16 + i;
            int ph = n / 24, pw = n - ph * 24;
            const float* base = x + b * 15552 + (3 * ph) * 72 + 3 * pw;
            float pix[3][9];
            #pragma unroll
            for (int c = 0; c < 3; ++c)
                #pragma unroll
                for (int ii = 0; ii < 3; ++ii)
                    #pragma unroll
                    for (int j = 0; j < 3; ++j)
                        pix[c][ii * 3 + j] = base[c * 5184 + ii * 72 + j];
            #pragma unroll
            for (int c = 0; c < 3; ++c)
                #pragma unroll
                for (int d = c; d < 3; ++d) {
                    float s = 0.0f;
                    #pragma unroll
                    for (int e = 0; e < 9; ++e) s += pix[c][e] * pix[d][e];
                    s = s / 27.0f;
                    p1sm[i * 9 + c * 3 + d] = s;
                    p1sm[i * 9 + d * 3 + c] = s;
                }
        }
    }
    __syncthreads();

    // ---------------- P2: score sweep, one wave per n ------------------------
    const int waveid = threadIdx.x >> 6;
    const int lane   = threadIdx.x & 63;
    const int n = group * 16 + waveid;

    float v1[9], v2[9];
    #pragma unroll
    for (int d = 0; d < 9; ++d) { v1[d] = p1sm[waveid * 9 + d]; v2[d] = qsm[n * 9 + d]; }
    float n1 = 0.0f, n2 = 0.0f;
    #pragma unroll
    for (int d = 0; d < 9; ++d) { n1 += v1[d] * v1[d]; n2 += v2[d] * v2[d]; }

    float best = 3.402823466e+38f;
    int bidx = 0x7fffffff;
    for (int m = lane; m < 756; m += 64) {
        const float* q = qsm + m * 9;
        float nq = 0.0f, d1 = 0.0f, d2 = 0.0f;
        #pragma unroll
        for (int d = 0; d < 9; ++d) {
            float qv = q[d];
            nq += qv * qv; d1 += v1[d] * qv; d2 += v2[d] * qv;
        }
        float s = fmaxf((n1 + nq) - 2.0f * d1, 0.0f) + fmaxf((n2 + nq) - 2.0f * d2, 0.0f);
        if (s < best) { best = s; bidx = m; }       // strict <: first-min within lane
    }
    // cross-lane argmin, ties -> smaller index (jnp.argmin first-occurrence)
    #pragma unroll
    for (int off = 32; off > 0; off >>= 1) {
        float ob = __shfl_down(best, off);
        int   oi = __shfl_down(bidx, off);
        if (ob < best || (ob == best && oi < bidx)) { best = ob; bidx = oi; }
    }
    if (lane == 0) {
        const float* q = qsm + bidx * 9;
        float s = 0.0f;
        #pragma unroll
        for (int d = 0; d < 9; ++d) s += fabsf(v1[d] - q[d]);
        wpart[waveid] = s;
    }
    __syncthreads();
    if (threadIdx.x == 0) {
        float s = 0.0f;
        #pragma unroll
        for (int w = 0; w < 16; ++w) s += wpart[w];
        ws[PART_OFF + blockIdx.x] = s;
    }
}

// ---------------- finalize: single wave sums 144 partials --------------------
__global__ void __launch_bounds__(64)
finalize_kernel(const float* __restrict__ ws, float* __restrict__ out) {
    int t = threadIdx.x;
    float s = ws[PART_OFF + t] + ws[PART_OFF + t + 64];
    if (t < 16) s += ws[PART_OFF + t + 128];
    #pragma unroll
    for (int off = 32; off > 0; off >>= 1) s += __shfl_down(s, off);
    if (t == 0) out[0] = s / 20736.0f;
}

extern "C" void kernel_launch(void* const* d_in, const int* in_sizes, int n_in,
                              void* d_out, int out_size, void* d_ws, size_t ws_size,
                              hipStream_t stream) {
    const float* x  = (const float*)d_in[0];
    const float* gt = (const float*)d_in[1];
    float* ws  = (float*)d_ws;
    float* out = (float*)d_out;

    fused_kernel<<<144, 1024, 0, stream>>>(x, gt, ws);
    finalize_kernel<<<1, 64, 0, stream>>>(ws, out);
}